// Round 10
// baseline (8221.886 us; speedup 1.0000x reference)
//
#include <hip/hip_runtime.h>
#include <hip/hip_bf16.h>
#include <cstdint>

// Problem constants: B=8, D=512, T=2048, K=8192. BT = 16384 queries.
constexpr int Dv = 512;
constexpr int Tv = 2048;
constexpr int Kv = 8192;
constexpr int BT = 16384;

// vq_main geometry: block = 512 thr = 8 waves. Lane = code (64 k per chunk),
// wave = 32 queries -> block covers 256 q. 64 panels x 12 subs = 768 blocks
// = exactly 3 blocks/CU, zero tail. Each sub owns 10-11 chunks of 64 k.
constexpr int NBLK = 768;

// ---------------------------------------------------------------- x_sq ----
__global__ void vq_xsq(const float* __restrict__ lat, float* __restrict__ xsq) {
    int q = blockIdx.x * 256 + threadIdx.x;      // 64 blocks x 256 = 16384
    int b = q >> 11, t = q & 2047;
    const float* p = lat + (size_t)b * Dv * Tv + t;
    float a = 0.f;
    #pragma unroll 8
    for (int d = 0; d < Dv; ++d) {
        float v = p[(size_t)d * Tv];
        a = fmaf(v, v, a);
    }
    xsq[q] = a;
}

// ---------------------------------------------------------------- e_sq ----
__global__ void vq_esq(const float* __restrict__ emb, float* __restrict__ esq) {
    int gid = blockIdx.x * 256 + threadIdx.x;
    int k = gid >> 6;                 // one wave per code row
    int l = threadIdx.x & 63;
    const float* p = emb + (size_t)k * Dv + l;
    float a = 0.f;
    #pragma unroll
    for (int i = 0; i < 8; ++i) {
        float v = p[i * 64];
        a = fmaf(v, v, a);
    }
    #pragma unroll
    for (int off = 32; off; off >>= 1) a += __shfl_down(a, off, 64);
    if (l == 0) esq[k] = a;
}

// ----------------------------------------------------------------- init ---
__global__ void vq_init(unsigned long long* __restrict__ keys) {
    int q = blockIdx.x * 256 + threadIdx.x;
    keys[q] = 0xFFFFFFFFFFFFFFFFull;
}

// ----------------------------------------------------------------- main ---
// k-per-lane: lane owns code k0+lane, wave owns 32 q, acc[32] regs.
// E chunk [64k][64d] double-buffered in LDS (rows padded to 68 floats:
// b128-aligned, (r+q)%8 bank spread = conflict floor; read offsets are
// compile-time immediates). X is wave-uniform -> scalar-load path (SMEM
// pipe, parallel to VALU; proven VGPR=28 codegen in round 9). Staging for
// chunk i+1 is issued BEFORE compute of chunk i (loads in flight under
// ~2048 cyc of FMA), ds_write lands after the barrier -> latency hidden.
// d-accumulation strictly sequential 0..511 -> bit-identical to np ref.
__global__ __launch_bounds__(512, 6) void vq_main(
        const float* __restrict__ lat, const float* __restrict__ emb,
        const float* __restrict__ xsq, const float* __restrict__ esq,
        unsigned long long* __restrict__ keys) {
    __shared__ float Es[2][64 * 68];              // 34816 B
    __shared__ unsigned long long bestlds[256];   // 2 KB

    const int tid  = threadIdx.x;
    const int lane = tid & 63;
    const int wid  = __builtin_amdgcn_readfirstlane(tid >> 6);  // wave 0..7
    const int bid  = blockIdx.x;
    const int panel = bid / 12;
    const int sub   = bid - panel * 12;
    const int q0    = panel * 256;
    const int b     = q0 >> 11;
    const int t0    = q0 & 2047;
    // 128 chunks of 64 k split 8x11 + 4x10
    const int cnt = (sub < 8) ? 11 : 10;
    const int kc0 = (sub < 8) ? sub * 11 : 88 + (sub - 8) * 10;

    if (tid < 256) bestlds[tid] = 0xFFFFFFFFFFFFFFFFull;

    // wave-uniform X base (readfirstlane keeps it on the scalar path)
    const float* latq = lat + (size_t)b * Dv * Tv + t0 + wid * 32;

    const int srow  = tid >> 3;        // 0..63 staging row (code)
    const int squad = (tid & 7) * 4;   // 0,4,..,28 staging d-quad

    for (int kc = kc0; kc < kc0 + cnt; ++kc) {
        const int k0 = kc * 64;
        const float esl = esq[k0 + lane];
        float acc[32];
        #pragma unroll
        for (int q = 0; q < 32; ++q) acc[q] = 0.f;

        // prologue: stage chunk dci=0 into Es[0]
        {
            const float* eb = emb + (size_t)(k0 + srow) * Dv + squad;
            float4 v0 = *(const float4*)(eb);
            float4 v1 = *(const float4*)(eb + 32);
            *(float4*)&Es[0][srow * 68 + squad] = v0;
            *(float4*)&Es[0][srow * 68 + 32 + squad] = v1;
            __syncthreads();
        }

        for (int dci = 0; dci < 8; ++dci) {
            const int cur = dci & 1;
            float4 v0n, v1n;
            const bool more = (dci < 7);
            if (more) {     // issue next-chunk loads; consumed ~2048 cyc later
                const float* eb = emb + (size_t)(k0 + srow) * Dv + (dci + 1) * 64 + squad;
                v0n = *(const float4*)(eb);
                v1n = *(const float4*)(eb + 32);
            }

            // compute on Es[cur]: 64 d x 32 q FMAs per wave
            const float* erow = &Es[cur][lane * 68];
            #pragma unroll
            for (int j = 0; j < 16; ++j) {
                const float4 e4 = *(const float4*)(erow + j * 4);
                const int dg = dci * 64 + j * 4;
                #define VQ_C(EC, DOFF) { \
                    const float4* xp = (const float4*)(latq + (size_t)(DOFF) * Tv); \
                    const float4 xa_ = xp[0], xb_ = xp[1], xc_ = xp[2], xd_ = xp[3]; \
                    const float4 xe_ = xp[4], xf_ = xp[5], xg_ = xp[6], xh_ = xp[7]; \
                    acc[0]  = fmaf(xa_.x, (EC), acc[0]);  acc[1]  = fmaf(xa_.y, (EC), acc[1]);  \
                    acc[2]  = fmaf(xa_.z, (EC), acc[2]);  acc[3]  = fmaf(xa_.w, (EC), acc[3]);  \
                    acc[4]  = fmaf(xb_.x, (EC), acc[4]);  acc[5]  = fmaf(xb_.y, (EC), acc[5]);  \
                    acc[6]  = fmaf(xb_.z, (EC), acc[6]);  acc[7]  = fmaf(xb_.w, (EC), acc[7]);  \
                    acc[8]  = fmaf(xc_.x, (EC), acc[8]);  acc[9]  = fmaf(xc_.y, (EC), acc[9]);  \
                    acc[10] = fmaf(xc_.z, (EC), acc[10]); acc[11] = fmaf(xc_.w, (EC), acc[11]); \
                    acc[12] = fmaf(xd_.x, (EC), acc[12]); acc[13] = fmaf(xd_.y, (EC), acc[13]); \
                    acc[14] = fmaf(xe_.x, (EC), acc[14]); acc[15] = fmaf(xe_.y, (EC), acc[15]); \
                    acc[16] = fmaf(xe_.z, (EC), acc[16]); acc[17] = fmaf(xe_.w, (EC), acc[17]); \
                    acc[18] = fmaf(xf_.x, (EC), acc[18]); acc[19] = fmaf(xf_.y, (EC), acc[19]); \
                    acc[20] = fmaf(xf_.z, (EC), acc[20]); acc[21] = fmaf(xf_.w, (EC), acc[21]); \
                    acc[22] = fmaf(xg_.x, (EC), acc[22]); acc[23] = fmaf(xg_.y, (EC), acc[23]); \
                    acc[24] = fmaf(xg_.z, (EC), acc[24]); acc[25] = fmaf(xg_.w, (EC), acc[25]); \
                    acc[26] = fmaf(xh_.x, (EC), acc[26]); acc[27] = fmaf(xh_.y, (EC), acc[27]); \
                    acc[28] = fmaf(xh_.z, (EC), acc[28]); acc[29] = fmaf(xh_.w, (EC), acc[29]); \
                    acc[30] = fmaf(xd_.z, (EC), acc[30]); acc[31] = fmaf(xd_.w, (EC), acc[31]); }
                // NOTE: acc index must equal q offset; fix ordering below.
                #undef VQ_C
                #define VQ_C(EC, DOFF) { \
                    const float4* xp = (const float4*)(latq + (size_t)(DOFF) * Tv); \
                    const float4 x0_ = xp[0], x1_ = xp[1], x2_ = xp[2], x3_ = xp[3]; \
                    const float4 x4_ = xp[4], x5_ = xp[5], x6_ = xp[6], x7_ = xp[7]; \
                    acc[0]  = fmaf(x0_.x, (EC), acc[0]);  acc[1]  = fmaf(x0_.y, (EC), acc[1]);  \
                    acc[2]  = fmaf(x0_.z, (EC), acc[2]);  acc[3]  = fmaf(x0_.w, (EC), acc[3]);  \
                    acc[4]  = fmaf(x1_.x, (EC), acc[4]);  acc[5]  = fmaf(x1_.y, (EC), acc[5]);  \
                    acc[6]  = fmaf(x1_.z, (EC), acc[6]);  acc[7]  = fmaf(x1_.w, (EC), acc[7]);  \
                    acc[8]  = fmaf(x2_.x, (EC), acc[8]);  acc[9]  = fmaf(x2_.y, (EC), acc[9]);  \
                    acc[10] = fmaf(x2_.z, (EC), acc[10]); acc[11] = fmaf(x2_.w, (EC), acc[11]); \
                    acc[12] = fmaf(x3_.x, (EC), acc[12]); acc[13] = fmaf(x3_.y, (EC), acc[13]); \
                    acc[14] = fmaf(x3_.z, (EC), acc[14]); acc[15] = fmaf(x3_.w, (EC), acc[15]); \
                    acc[16] = fmaf(x4_.x, (EC), acc[16]); acc[17] = fmaf(x4_.y, (EC), acc[17]); \
                    acc[18] = fmaf(x4_.z, (EC), acc[18]); acc[19] = fmaf(x4_.w, (EC), acc[19]); \
                    acc[20] = fmaf(x5_.x, (EC), acc[20]); acc[21] = fmaf(x5_.y, (EC), acc[21]); \
                    acc[22] = fmaf(x5_.z, (EC), acc[22]); acc[23] = fmaf(x5_.w, (EC), acc[23]); \
                    acc[24] = fmaf(x6_.x, (EC), acc[24]); acc[25] = fmaf(x6_.y, (EC), acc[25]); \
                    acc[26] = fmaf(x6_.z, (EC), acc[26]); acc[27] = fmaf(x6_.w, (EC), acc[27]); \
                    acc[28] = fmaf(x7_.x, (EC), acc[28]); acc[29] = fmaf(x7_.y, (EC), acc[29]); \
                    acc[30] = fmaf(x7_.z, (EC), acc[30]); acc[31] = fmaf(x7_.w, (EC), acc[31]); }
                VQ_C(e4.x, dg + 0)
                VQ_C(e4.y, dg + 1)
                VQ_C(e4.z, dg + 2)
                VQ_C(e4.w, dg + 3)
                #undef VQ_C
            }
            __syncthreads();            // all waves done reading Es[cur]
            if (more) {
                *(float4*)&Es[cur ^ 1][srow * 68 + squad] = v0n;
                *(float4*)&Es[cur ^ 1][srow * 68 + 32 + squad] = v1n;
                __syncthreads();        // next buffer ready
            }
        }

        // dist + argmin for this chunk. dist = fl(fl(xs - 2c) + es):
        // fmaf(-2,c,xs) == xs - (2*c) exactly (2c exact). Packed u64 key ->
        // lexicographic (dist, k) min == np.argmin first-index rule.
        #pragma unroll
        for (int q = 0; q < 32; ++q) {
            const float xs = xsq[q0 + wid * 32 + q];   // wave-uniform scalar
            float dist = fmaf(-2.0f, acc[q], xs) + esl;
            unsigned long long key =
                ((unsigned long long)__float_as_uint(dist) << 32)
                | (unsigned int)(k0 + lane);
            #pragma unroll
            for (int off = 32; off; off >>= 1) {
                unsigned long long o = __shfl_xor(key, off, 64);
                key = (o < key) ? o : key;
            }
            if (lane == 0) {
                if (key < bestlds[wid * 32 + q]) bestlds[wid * 32 + q] = key;
            }
        }
    }

    __syncthreads();
    if (tid < 256) atomicMin(&keys[q0 + tid], bestlds[tid]);
}

// --------------------------------------------------------------- gather ---
// out[b][d][t] = emb[idx[b*T+t]][d]; lanes along t -> coalesced stores.
__global__ void vq_gather(const float* __restrict__ emb,
                          const unsigned long long* __restrict__ keys,
                          float* __restrict__ out) {
    int blk = blockIdx.x;            // 256 blocks of 64 queries
    int tid = threadIdx.x;
    int tl = tid & 63, dg = tid >> 6;   // dg in [0,4)
    int q = blk * 64 + tl;
    int b = q >> 11, t = q & 2047;
    int idx = (int)(keys[q] & 0xFFFFFFFFull);
    const float* er = emb + (size_t)idx * Dv + dg * 128;
    float* ob = out + ((size_t)b * Dv + dg * 128) * Tv + t;
    #pragma unroll 8
    for (int i = 0; i < 128; ++i) ob[(size_t)i * Tv] = er[i];
}

// ---------------------------------------------------------------------------
extern "C" void kernel_launch(void* const* d_in, const int* in_sizes, int n_in,
                              void* d_out, int out_size, void* d_ws, size_t ws_size,
                              hipStream_t stream) {
    (void)in_sizes; (void)n_in; (void)out_size; (void)ws_size;
    const float* lat = (const float*)d_in[0];   // [8, 512, 2048]
    const float* emb = (const float*)d_in[1];   // [8192, 512]
    float* out = (float*)d_out;                 // [8, 512, 2048]

    char* ws = (char*)d_ws;
    float* xsq = (float*)(ws);                                   // 64 KB
    float* esq = (float*)(ws + (64 << 10));                      // 32 KB
    unsigned long long* keys =
        (unsigned long long*)(ws + (96 << 10));                  // 128 KB

    vq_init <<<BT / 256, 256, 0, stream>>>(keys);
    vq_xsq  <<<BT / 256, 256, 0, stream>>>(lat, xsq);
    vq_esq  <<<Kv / 4,   256, 0, stream>>>(emb, esq);
    vq_main <<<NBLK, 512, 0, stream>>>(lat, emb, xsq, esq, keys);
    vq_gather<<<BT / 64, 256, 0, stream>>>(emb, keys, out);
}

// Round 11
// 4548.732 us; speedup vs baseline: 1.8075x; 1.8075x over previous
//
#include <hip/hip_runtime.h>
#include <hip/hip_bf16.h>
#include <cstdint>

// Problem constants: B=8, D=512, T=2048, K=8192. BT = 16384 queries.
constexpr int Dv = 512;
constexpr int Tv = 2048;
constexpr int Kv = 8192;
constexpr int BT = 16384;
constexpr unsigned CAP = 4u << 20;     // candidate buffer entries (32 MB)

typedef __bf16 v8bf __attribute__((ext_vector_type(8)));
typedef float  f32x4 __attribute__((ext_vector_type(4)));
typedef unsigned long long u64;

// margin2(q) = 2*M_q: bf16 rel err 2^-8 per operand -> |2c_err| <= 2^-6*S/8192
// = 1.907e-6*S; + fl(dist) rounding slack (2 ulp @512 ~1.3e-4) + key-shift pad.
__device__ __forceinline__ float margin2(float S) {
    return 3.9e-6f * S + 3.2e-4f;
}

// ------------------------------------------------------------- x_sq + S ---
__global__ void vq_xsq(const float* __restrict__ lat, float* __restrict__ xsq,
                       float* __restrict__ Ssum) {
    int q = blockIdx.x * 256 + threadIdx.x;
    int b = q >> 11, t = q & 2047;
    const float* p = lat + (size_t)b * Dv * Tv + t;
    float a = 0.f, s = 0.f;
    #pragma unroll 8
    for (int d = 0; d < Dv; ++d) {
        float v = p[(size_t)d * Tv];
        a = fmaf(v, v, a);        // EXACT same chain as all passing rounds
        s = s + fabsf(v);         // independent accumulator (margin only)
    }
    xsq[q] = a;
    Ssum[q] = s;
}

// ---------------------------------------------------------------- e_sq ----
__global__ void vq_esq(const float* __restrict__ emb, float* __restrict__ esq) {
    int gid = blockIdx.x * 256 + threadIdx.x;
    int k = gid >> 6;
    int l = threadIdx.x & 63;
    const float* p = emb + (size_t)k * Dv + l;
    float a = 0.f;
    #pragma unroll
    for (int i = 0; i < 8; ++i) {
        float v = p[i * 64];
        a = fmaf(v, v, a);
    }
    #pragma unroll
    for (int off = 32; off; off >>= 1) a += __shfl_down(a, off, 64);
    if (l == 0) esq[k] = a;
}

// ----------------------------------------------------------------- init ---
__global__ void vq_init_keys(u64* __restrict__ keys) {
    int q = blockIdx.x * 256 + threadIdx.x;
    keys[q] = 0xFFFFFFFFFFFFFFFFull;
}
__global__ void vq_init_aux(unsigned* __restrict__ qmin, unsigned* __restrict__ ctr) {
    int q = blockIdx.x * 256 + threadIdx.x;
    qmin[q] = 0xFFFFFFFFu;
    if (q == 0) *ctr = 0u;
}

// ------------------------------------------------------------ bf16 cvt ----
// Ebf[k][d] row-major bf16
__global__ void vq_cvt_e(const float* __restrict__ emb, ushort* __restrict__ Ebf) {
    int i = blockIdx.x * 256 + threadIdx.x;       // 2048 blocks: i*8 elems
    const float4 v0 = *(const float4*)(emb + (size_t)i * 8);
    const float4 v1 = *(const float4*)(emb + (size_t)i * 8 + 4);
    ushort o[8];
    float f[8] = {v0.x, v0.y, v0.z, v0.w, v1.x, v1.y, v1.z, v1.w};
    #pragma unroll
    for (int j = 0; j < 8; ++j) {
        __hip_bfloat16 h = __float2bfloat16(f[j]);   // RNE
        o[j] = *(ushort*)&h;
    }
    *(uint4*)(Ebf + (size_t)i * 8) = *(uint4*)o;
}

// Xbf[q][d] row-major bf16, transposed from lat [b][d][t]
__global__ void vq_cvt_x(const float* __restrict__ lat, ushort* __restrict__ Xbf) {
    __shared__ float Xs[64][65];
    int blk = blockIdx.x;               // 2048 = 8 b x 8 dblk x 32 tblk
    int tb = blk & 31, db = (blk >> 5) & 7, b = blk >> 8;
    int d0 = db * 64, t0 = tb * 64;
    int tid = threadIdx.x;
    // read: coalesced along t
    #pragma unroll
    for (int i = 0; i < 4; ++i) {
        int r = (tid >> 4) + i * 16;
        int c = (tid & 15) * 4;
        float4 v = *(const float4*)(lat + ((size_t)(b * Dv + d0 + r)) * Tv + t0 + c);
        Xs[r][c] = v.x; Xs[r][c + 1] = v.y; Xs[r][c + 2] = v.z; Xs[r][c + 3] = v.w;
    }
    __syncthreads();
    // write: Xbf rows d-contiguous
    int tt = tid >> 2, dg = tid & 3;
    int q = b * Tv + t0 + tt;
    #pragma unroll
    for (int i = 0; i < 2; ++i) {
        ushort o[8];
        #pragma unroll
        for (int j = 0; j < 8; ++j) {
            __hip_bfloat16 h = __float2bfloat16(Xs[dg * 16 + i * 8 + j][tt]);
            o[j] = *(ushort*)&h;
        }
        *(uint4*)(Xbf + (size_t)q * Dv + d0 + dg * 16 + i * 8) = *(uint4*)o;
    }
}

// ------------------------------------------------------- pass A: MFMA -----
// 128x128 tile, 4 waves (2x2), wave-tile 64x64 = 4x4 frags of 16x16x32 bf16.
// A/B staged identically d-contiguous -> k-permutation-invariant dot.
// Epilogue: key = (es - 2c) + 1.0 (positive, uint-monotone); per-q tile min,
// qmin atomicMin, candidate append within margin (covers exact argmin: proof
// via |approx-exact| <= M on both tilemin and qmin sides).
__global__ void vq_mfma(const ushort* __restrict__ Xbf, const ushort* __restrict__ Ebf,
                        const float* __restrict__ es, const float* __restrict__ Ssum,
                        unsigned* __restrict__ qmin, u64* __restrict__ cand,
                        unsigned* __restrict__ ctr) {
    __shared__ ushort Abuf[128 * 40];   // row pitch 40 elems (80 B): pad kills conflicts
    __shared__ ushort Bbuf[128 * 40];
    __shared__ unsigned tminl[128];
    __shared__ float thrl[128];

    const int tid = threadIdx.x;
    const int bid = blockIdx.x;                 // 8192 = 128 qt x 64 kt, kt inner
    const int q0 = (bid >> 6) * 128;
    const int k0 = (bid & 63) * 128;
    const int w = tid >> 6, l = tid & 63;
    const int wr = w >> 1, wc = w & 1;

    const int ar = tid >> 1, ah = tid & 1;      // staging: 2 thr/row, 32 B each

    f32x4 acc[4][4] = {};

    const ushort* Ag = Xbf + (size_t)(q0 + ar) * Dv + ah * 16;
    const ushort* Bg = Ebf + (size_t)(k0 + ar) * Dv + ah * 16;

    uint4 pa0 = *(const uint4*)(Ag);
    uint4 pa1 = *(const uint4*)(Ag + 8);
    uint4 pb0 = *(const uint4*)(Bg);
    uint4 pb1 = *(const uint4*)(Bg + 8);

    for (int s = 0; s < 16; ++s) {
        __syncthreads();
        *(uint4*)&Abuf[ar * 40 + ah * 16] = pa0;
        *(uint4*)&Abuf[ar * 40 + ah * 16 + 8] = pa1;
        *(uint4*)&Bbuf[ar * 40 + ah * 16] = pb0;
        *(uint4*)&Bbuf[ar * 40 + ah * 16 + 8] = pb1;
        __syncthreads();
        if (s < 15) {
            int d0 = (s + 1) * 32;
            pa0 = *(const uint4*)(Ag + d0);
            pa1 = *(const uint4*)(Ag + d0 + 8);
            pb0 = *(const uint4*)(Bg + d0);
            pb1 = *(const uint4*)(Bg + d0 + 8);
        }
        v8bf afr[4], bfc[4];
        #pragma unroll
        for (int f = 0; f < 4; ++f) {
            int arow = wr * 64 + f * 16 + (l & 15);
            afr[f] = __builtin_bit_cast(v8bf, *(const uint4*)&Abuf[arow * 40 + (l >> 4) * 8]);
            int brow = wc * 64 + f * 16 + (l & 15);
            bfc[f] = __builtin_bit_cast(v8bf, *(const uint4*)&Bbuf[brow * 40 + (l >> 4) * 8]);
        }
        #pragma unroll
        for (int fr = 0; fr < 4; ++fr)
            #pragma unroll
            for (int fc = 0; fc < 4; ++fc)
                acc[fr][fc] = __builtin_amdgcn_mfma_f32_16x16x32_bf16(
                    afr[fr], bfc[fc], acc[fr][fc], 0, 0, 0);
    }

    // ---------------- epilogue ----------------
    if (tid < 128) tminl[tid] = 0xFFFFFFFFu;
    __syncthreads();

    float esv[4];
    #pragma unroll
    for (int fc = 0; fc < 4; ++fc) esv[fc] = es[k0 + wc * 64 + fc * 16 + (l & 15)];

    #pragma unroll
    for (int fr = 0; fr < 4; ++fr) {
        float rmin[4] = {3.4e38f, 3.4e38f, 3.4e38f, 3.4e38f};
        #pragma unroll
        for (int fc = 0; fc < 4; ++fc)
            #pragma unroll
            for (int v = 0; v < 4; ++v) {
                float kf = fmaf(-2.0f, acc[fr][fc][v], esv[fc]) + 1.0f;
                rmin[v] = fminf(rmin[v], kf);
            }
        #pragma unroll
        for (int v = 0; v < 4; ++v) {
            float m = rmin[v];
            m = fminf(m, __shfl_xor(m, 1, 64));
            m = fminf(m, __shfl_xor(m, 2, 64));
            m = fminf(m, __shfl_xor(m, 4, 64));
            m = fminf(m, __shfl_xor(m, 8, 64));
            if ((l & 15) == 0)
                atomicMin(&tminl[wr * 64 + fr * 16 + (l >> 4) * 4 + v], __float_as_uint(m));
        }
    }
    __syncthreads();
    if (tid < 128) {
        unsigned tm = tminl[tid];
        unsigned old = atomicMin(&qmin[q0 + tid], tm);
        unsigned eff = old < tm ? old : tm;
        thrl[tid] = __uint_as_float(eff) + margin2(Ssum[q0 + tid]);
    }
    __syncthreads();
    #pragma unroll
    for (int fr = 0; fr < 4; ++fr)
        #pragma unroll
        for (int fc = 0; fc < 4; ++fc)
            #pragma unroll
            for (int v = 0; v < 4; ++v) {
                float kf = fmaf(-2.0f, acc[fr][fc][v], esv[fc]) + 1.0f;
                int qloc = wr * 64 + fr * 16 + (l >> 4) * 4 + v;
                if (kf <= thrl[qloc]) {
                    unsigned id = atomicAdd(ctr, 1u);
                    if (id < CAP) {
                        int kk = k0 + wc * 64 + fc * 16 + (l & 15);
                        cand[id] = ((u64)__float_as_uint(kf) << 32)
                                 | ((u64)(unsigned)(q0 + qloc) << 13) | (unsigned)kk;
                    }
                }
            }
}

// ---------------------------------------------------- exact rescore -------
// Survivors (within final qmin + margin) rescored with the EXACT sequential
// fp32 d-chain (same rounding as np ref / prior passing rounds); packed
// (dist,k) u64 atomicMin == np.argmin first-index tie rule.
__global__ void vq_rescore(const float* __restrict__ lat, const float* __restrict__ emb,
                           const float* __restrict__ xs, const float* __restrict__ es,
                           const float* __restrict__ Ssum,
                           const unsigned* __restrict__ qmin,
                           const u64* __restrict__ cand, const unsigned* __restrict__ ctr,
                           u64* __restrict__ keys) {
    unsigned total = *ctr;
    if (total > CAP) total = CAP;
    for (unsigned i = blockIdx.x * 256 + threadIdx.x; i < total; i += 4096 * 256) {
        u64 c = cand[i];
        float kf = __uint_as_float((unsigned)(c >> 32));
        int q = (int)((c >> 13) & 16383u);
        int k = (int)(c & 8191u);
        float thr = __uint_as_float(qmin[q]) + margin2(Ssum[q]);
        if (kf > thr) continue;
        int b = q >> 11, t = q & 2047;
        const float* xr = lat + (size_t)b * Dv * Tv + t;
        const float* er = emb + (size_t)k * Dv;
        float cc = 0.f;
        #pragma unroll 8
        for (int d = 0; d < Dv; ++d)
            cc = fmaf(xr[(size_t)d * Tv], er[d], cc);   // strict sequential chain
        float dist = fmaf(-2.0f, cc, xs[q]) + es[k];
        u64 key = ((u64)__float_as_uint(dist) << 32) | (unsigned)k;
        atomicMin(&keys[q], key);
    }
}

// --------------------------------------------------------------- gather ---
__global__ void vq_gather(const float* __restrict__ emb, const u64* __restrict__ keys,
                          float* __restrict__ out) {
    int blk = blockIdx.x;
    int tid = threadIdx.x;
    int tl = tid & 63, dg = tid >> 6;
    int q = blk * 64 + tl;
    int b = q >> 11, t = q & 2047;
    int idx = (int)(keys[q] & 0xFFFFFFFFull);
    const float* er = emb + (size_t)idx * Dv + dg * 128;
    float* ob = out + ((size_t)b * Dv + dg * 128) * Tv + t;
    #pragma unroll 8
    for (int i = 0; i < 128; ++i) ob[(size_t)i * Tv] = er[i];
}

// ================= FALLBACK: round-3 exact path (proven, 1873 us) =========
constexpr int FBQ = 128, FBK = 128, FBD = 32, FBPQ = 6;
__global__ __launch_bounds__(256, 3) void vq_main_exact(
        const float* __restrict__ lat, const float* __restrict__ emb,
        const float* __restrict__ xsq, const float* __restrict__ esq,
        u64* __restrict__ keys) {
    __shared__ float Xs[FBD][FBQ];
    __shared__ float Es[FBD][FBK];
    const int tid = threadIdx.x, bid = blockIdx.x;
    const int qb = bid / FBPQ, sub = bid - qb * FBPQ;
    const int q0 = qb * FBQ, b = q0 >> 11, t0 = q0 & 2047;
    const int cnt = (sub < 4) ? 11 : 10;
    const int kc0 = (sub < 4) ? sub * 11 : 44 + (sub - 4) * 10;
    const int tx = (tid & 7) | (((tid >> 6) & 1) << 3);
    const int ty = ((tid >> 3) & 7) | (((tid >> 7) & 1) << 3);
    const int sq = tid & 31, srow = tid >> 5;
    const int dq = tid & 7, ekk = tid >> 3, fsw = dq << 2;
    float best[8]; int bidx[8]; float xsv[8];
    #pragma unroll
    for (int i = 0; i < 8; ++i) {
        best[i] = 3.4e38f; bidx[i] = 0x7fffffff; xsv[i] = xsq[q0 + ty * 8 + i];
    }
    const float* latb = lat + (size_t)b * Dv * Tv + t0;
    float* const esw = &Es[0][0];
    for (int kc = kc0; kc < kc0 + cnt; ++kc) {
        const int k0 = kc * FBK;
        float c[8][8];
        #pragma unroll
        for (int i = 0; i < 8; ++i)
            #pragma unroll
            for (int j = 0; j < 8; ++j) c[i][j] = 0.f;
        for (int dc = 0; dc < Dv / FBD; ++dc) {
            const int d0 = dc * FBD;
            __syncthreads();
            #pragma unroll
            for (int i = 0; i < 4; ++i) {
                int dd = srow + i * 8;
                float4 v = *(const float4*)(latb + (size_t)(d0 + dd) * Tv + sq * 4);
                *(float4*)&Xs[dd][sq * 4] = v;
            }
            #pragma unroll
            for (int i = 0; i < 4; ++i) {
                int kk = ekk + i * 32;
                float4 v = *(const float4*)(emb + (size_t)(k0 + kk) * Dv + d0 + dq * 4);
                int ksw = kk ^ fsw;
                esw[(dq * 4 + 0) * FBK + ksw] = v.x;
                esw[(dq * 4 + 1) * FBK + ksw] = v.y;
                esw[(dq * 4 + 2) * FBK + ksw] = v.z;
                esw[(dq * 4 + 3) * FBK + ksw] = v.w;
            }
            __syncthreads();
            #pragma unroll 4
            for (int dd = 0; dd < FBD; ++dd) {
                const int g = (dd >> 2) << 2;
                const float4 xa = *(const float4*)&Xs[dd][ty * 8];
                const float4 xb = *(const float4*)&Xs[dd][ty * 8 + 4];
                const float4 ea = *(const float4*)&esw[dd * FBK + ((tx * 8) ^ g)];
                const float4 eb = *(const float4*)&esw[dd * FBK + ((tx * 8 + 4) ^ g)];
                #define VQ_ROW(i, XV)                       \
                    c[i][0] = fmaf(XV, ea.x, c[i][0]);      \
                    c[i][1] = fmaf(XV, ea.y, c[i][1]);      \
                    c[i][2] = fmaf(XV, ea.z, c[i][2]);      \
                    c[i][3] = fmaf(XV, ea.w, c[i][3]);      \
                    c[i][4] = fmaf(XV, eb.x, c[i][4]);      \
                    c[i][5] = fmaf(XV, eb.y, c[i][5]);      \
                    c[i][6] = fmaf(XV, eb.z, c[i][6]);      \
                    c[i][7] = fmaf(XV, eb.w, c[i][7]);
                VQ_ROW(0, xa.x) VQ_ROW(1, xa.y) VQ_ROW(2, xa.z) VQ_ROW(3, xa.w)
                VQ_ROW(4, xb.x) VQ_ROW(5, xb.y) VQ_ROW(6, xb.z) VQ_ROW(7, xb.w)
                #undef VQ_ROW
            }
        }
        float es8[8];
        #pragma unroll
        for (int j = 0; j < 8; ++j) es8[j] = esq[k0 + tx * 8 + j];
        #pragma unroll
        for (int i = 0; i < 8; ++i)
            #pragma unroll
            for (int j = 0; j < 8; ++j) {
                float dist = fmaf(-2.0f, c[i][j], xsv[i]) + es8[j];
                int kk = k0 + tx * 8 + j;
                if (dist < best[i]) { best[i] = dist; bidx[i] = kk; }
            }
    }
    __syncthreads();
    float* redv = &Xs[0][0];
    int* redi = (int*)&Es[0][0];
    #pragma unroll
    for (int i = 0; i < 8; ++i) {
        redv[(ty * 16 + tx) * 8 + i] = best[i];
        redi[(ty * 16 + tx) * 8 + i] = bidx[i];
    }
    __syncthreads();
    if (tid < 128) {
        int yy = tid >> 3, ii = tid & 7;
        float bv = 3.4e38f; int bi = 0x7fffffff;
        #pragma unroll
        for (int t = 0; t < 16; ++t) {
            float v = redv[(yy * 16 + t) * 8 + ii];
            int ix = redi[(yy * 16 + t) * 8 + ii];
            if (v < bv || (v == bv && ix < bi)) { bv = v; bi = ix; }
        }
        int q = q0 + yy * 8 + ii;
        u64 key = ((u64)__float_as_uint(bv) << 32) | (unsigned)bi;
        atomicMin(&keys[q], key);
    }
}

// ---------------------------------------------------------------------------
extern "C" void kernel_launch(void* const* d_in, const int* in_sizes, int n_in,
                              void* d_out, int out_size, void* d_ws, size_t ws_size,
                              hipStream_t stream) {
    (void)in_sizes; (void)n_in; (void)out_size;
    const float* lat = (const float*)d_in[0];
    const float* emb = (const float*)d_in[1];
    float* out = (float*)d_out;

    char* ws = (char*)d_ws;
    float*    xs   = (float*)(ws);                       // 64 KB
    float*    Ssum = (float*)(ws + (64 << 10));          // 64 KB
    float*    es   = (float*)(ws + (128 << 10));         // 32 KB
    unsigned* qmin = (unsigned*)(ws + (160 << 10));      // 64 KB
    u64*      keys = (u64*)(ws + (224 << 10));           // 128 KB
    unsigned* ctr  = (unsigned*)(ws + (352 << 10));      // 4 KB slot
    u64*      cand = (u64*)(ws + (384 << 10));           // 32 MB
    ushort*   Xbf  = (ushort*)(ws + (384 << 10) + ((size_t)32 << 20));  // 16 MB
    ushort*   Ebf  = (ushort*)(ws + (384 << 10) + ((size_t)48 << 20));  // 8 MB
    const size_t need = ((size_t)384 << 10) + ((size_t)56 << 20) + ((size_t)1 << 20);

    vq_init_keys<<<BT / 256, 256, 0, stream>>>(keys);
    vq_xsq<<<BT / 256, 256, 0, stream>>>(lat, xs, Ssum);
    vq_esq<<<Kv / 4, 256, 0, stream>>>(emb, es);

    if (ws_size >= need) {
        vq_init_aux<<<BT / 256, 256, 0, stream>>>(qmin, ctr);
        vq_cvt_e<<<2048, 256, 0, stream>>>(emb, Ebf);
        vq_cvt_x<<<2048, 256, 0, stream>>>(lat, Xbf);
        vq_mfma<<<8192, 256, 0, stream>>>(Xbf, Ebf, es, Ssum, qmin, cand, ctr);
        vq_rescore<<<4096, 256, 0, stream>>>(lat, emb, xs, es, Ssum, qmin, cand, ctr, keys);
    } else {
        vq_main_exact<<<(BT / FBQ) * FBPQ, 256, 0, stream>>>(lat, emb, xs, es, keys);
    }
    vq_gather<<<BT / 64, 256, 0, stream>>>(emb, keys, out);
}